// Round 8
// baseline (281.122 us; speedup 1.0000x reference)
//
#include <hip/hip_runtime.h>
#include <hip/hip_bf16.h>

#define BB 32
#define NN 1024
#define MM 1024
#define DD 128

typedef __bf16 bf16;
typedef bf16 bf16x8 __attribute__((ext_vector_type(8)));
typedef bf16 bf16x4 __attribute__((ext_vector_type(4)));
typedef float f32x4 __attribute__((ext_vector_type(4)));

#define LOG2E 1.4426950408889634f
#define LN2   0.6931471805599453f
#define ESHIFT 30.5f
#define ESHIFT_C 5.6757e-14f   // exp(-30.5) EXACTLY -> softplus(x) = 30.5 + ln(E)

typedef __attribute__((address_space(1))) const void gvoid_t;
typedef __attribute__((address_space(3))) void lvoid_t;

__device__ __forceinline__ bf16x8 ld8(const bf16* p) {
    return *reinterpret_cast<const bf16x8*>(p);
}

__device__ __forceinline__ bf16x8 cvt8(const float* p) {
    float4 a = reinterpret_cast<const float4*>(p)[0];
    float4 c = reinterpret_cast<const float4*>(p)[1];
    bf16x8 r;
    r[0]=(bf16)a.x; r[1]=(bf16)a.y; r[2]=(bf16)a.z; r[3]=(bf16)a.w;
    r[4]=(bf16)c.x; r[5]=(bf16)c.y; r[6]=(bf16)c.z; r[7]=(bf16)c.w;
    return r;
}

// ---------- prep: Ys->bf16 + Ys^T + Xs^T (unchanged from round 7) ----------
__global__ __launch_bounds__(256) void k_prep(
    const float* __restrict__ Xs, const float* __restrict__ Ys,
    bf16* __restrict__ Ysb, bf16* __restrict__ YsT, bf16* __restrict__ XsT) {
    __shared__ float tile[64][65];
    int L = blockIdx.x;                  // 0..2047
    int xcd = L & 7, sidx = L >> 3;
    int b = xcd + 8 * (sidx & 3);        // batch -> fixed XCD (matches k_main)
    int t = sidx >> 2;                   // 0..63
    int isY = (t < 32);
    int tt = t & 31;
    int mtile = tt >> 1, dtile = tt & 1;
    int r0 = mtile * 64, d0 = dtile * 64;
    int tid = threadIdx.x;
    const float* src = (isY ? Ys : Xs) + (size_t)b * 1024 * DD;

    int rr = tid >> 4;                   // 0..15
    int c4 = (tid & 15) * 4;             // 0..60
#pragma unroll
    for (int p = 0; p < 4; ++p) {
        int row = p * 16 + rr;
        float4 v = *reinterpret_cast<const float4*>(src + (size_t)(r0 + row) * DD + d0 + c4);
        tile[row][c4] = v.x; tile[row][c4 + 1] = v.y;
        tile[row][c4 + 2] = v.z; tile[row][c4 + 3] = v.w;
        if (isY) {
            bf16x4 o; o[0] = (bf16)v.x; o[1] = (bf16)v.y; o[2] = (bf16)v.z; o[3] = (bf16)v.w;
            *reinterpret_cast<bf16x4*>(Ysb + (size_t)b * MM * DD + (size_t)(r0 + row) * DD + d0 + c4) = o;
        }
    }
    __syncthreads();
    bf16* dT = (isY ? YsT : XsT) + (size_t)b * DD * 1024;
#pragma unroll
    for (int q = 0; q < 2; ++q) {
        int d = q * 32 + (tid >> 3);     // 0..63 within d-tile
        int m0 = (tid & 7) * 8;          // 8-lane group covers 64 m = 128 B
        bf16x8 o;
#pragma unroll
        for (int j = 0; j < 8; ++j) o[j] = (bf16)tile[m0 + j][d];
        *reinterpret_cast<bf16x8*>(dT + (size_t)(d0 + d) * 1024 + r0 + m0) = o;
    }
}

// ---------- coeff: Xc = Xs * tanh(W @ A_w^T + A_b) (unchanged from round 7) ----------
__global__ __launch_bounds__(256) void k_coeff(
    const float* __restrict__ Xs, const float* __restrict__ W,
    const float* __restrict__ Aw, const float* __restrict__ Ab,
    bf16* __restrict__ Xc) {
    __shared__ bf16 cf[64][136];
    int L = blockIdx.x;                  // 0..511
    int xcd = L & 7, sidx = L >> 3;
    int b = xcd + 8 * (sidx & 3);
    int ntile = sidx >> 2;               // 0..15
    int tid = threadIdx.x;
    int w = tid >> 6, lane = tid & 63, quad = lane >> 4, l16 = lane & 15;
    int nbase = ntile * 64 + w * 16;

    f32x4 accZ[8];
#pragma unroll
    for (int ef = 0; ef < 8; ++ef) accZ[ef] = {0.f, 0.f, 0.f, 0.f};

    const float* Wb = W + ((size_t)b * NN + nbase + l16) * DD;
#pragma unroll
    for (int ks = 0; ks < 4; ++ks) {
        bf16x8 aW = cvt8(Wb + ks * 32 + quad * 8);
#pragma unroll
        for (int ef = 0; ef < 8; ++ef) {
            bf16x8 bA = cvt8(Aw + (size_t)(ef * 16 + l16) * DD + ks * 32 + quad * 8);
            accZ[ef] = __builtin_amdgcn_mfma_f32_16x16x32_bf16(aW, bA, accZ[ef], 0, 0, 0);
        }
    }
#pragma unroll
    for (int ef = 0; ef < 8; ++ef) {
        float ab = Ab[ef * 16 + l16];
#pragma unroll
        for (int r = 0; r < 4; ++r) {
            float z = accZ[ef][r] + ab;
            z = fminf(fmaxf(z, -12.f), 12.f);
            float t = __builtin_amdgcn_exp2f(z * (2.f * LOG2E));
            float c = (t - 1.f) / (t + 1.f);
            cf[w * 16 + quad * 4 + r][ef * 16 + l16] = (bf16)c;
        }
    }
    __syncthreads();
    const float* Xs_b = Xs + ((size_t)b * NN + ntile * 64) * DD;
    bf16* Xc_b = Xc + ((size_t)b * NN + ntile * 64) * DD;
    int row = tid >> 4, colg = (tid & 15) * 8;
#pragma unroll
    for (int p = 0; p < 4; ++p) {
        int rrow = p * 16 + row;
        float4 xa = *reinterpret_cast<const float4*>(Xs_b + (size_t)rrow * DD + colg);
        float4 xb = *reinterpret_cast<const float4*>(Xs_b + (size_t)rrow * DD + colg + 4);
        bf16x8 cv = *reinterpret_cast<const bf16x8*>(&cf[rrow][colg]);
        bf16x8 o;
        o[0] = (bf16)(xa.x * (float)cv[0]); o[1] = (bf16)(xa.y * (float)cv[1]);
        o[2] = (bf16)(xa.z * (float)cv[2]); o[3] = (bf16)(xa.w * (float)cv[3]);
        o[4] = (bf16)(xb.x * (float)cv[4]); o[5] = (bf16)(xb.y * (float)cv[5]);
        o[6] = (bf16)(xb.z * (float)cv[6]); o[7] = (bf16)(xb.w * (float)cv[7]);
        *reinterpret_cast<bf16x8*>(Xc_b + (size_t)rrow * DD + colg) = o;
    }
}

// ---------- merged main: global_load_lds staging + softplus-from-E identity ----------
// Round-6 double-buffered structure with two changes:
// (1) staging via __builtin_amdgcn_global_load_lds width=16: linear LDS dest,
//     inverse-swizzled per-lane SOURCE (involution o^(((o>>8)&7)<<4)) -> LDS
//     contents byte-identical to round 6, read-side addressing unchanged.
// (2) softplus(x) = ESHIFT + ln(E) exactly (ESHIFT_C == e^-ESHIFT), so the s
//     output is one log2 + one fma from the already-computed E.
__global__ __launch_bounds__(256, 2) void k_main(
    const bf16* __restrict__ Xc, const bf16* __restrict__ Ysb,
    const bf16* __restrict__ YsT, const bf16* __restrict__ XsT,
    float* __restrict__ out_x, float* __restrict__ out_y,
    float* __restrict__ out_s) {
    __shared__ __align__(16) bf16 stage[2][16384];   // 2 x 32 KB: [0:16K)=B, [16K:32K)=BT
    __shared__ __align__(16) bf16 Et[4][16][72];     // 9 KB, wave-private

    int L = blockIdx.x + 32 * blockIdx.y;            // 0..1023
    int xcd = L & 7, sidx = L >> 3;
    int b = xcd + 8 * (sidx & 3);                    // batch -> fixed XCD (L2 homing)
    int t = sidx >> 2;
    int role = t >> 4, tile = t & 15;
    int tid = threadIdx.x;
    int w = tid >> 6, lane = tid & 63, quad = lane >> 4, l16 = lane & 15;
    int rbase = tile * 64 + w * 16;

    const bf16* Arow  = (role == 0 ? Xc : Ysb) + ((size_t)b * 1024 + rbase + l16) * DD;
    const bf16* Bmat  = (role == 0 ? Ysb : Xc) + (size_t)b * 1024 * DD;
    const bf16* BTmat = (role == 0 ? YsT : XsT) + (size_t)b * DD * 1024;
    float* s_b = out_s + (size_t)b * NN * MM;
    float* outp = (role == 0 ? out_x : out_y);

    bf16x8 aX[4];
#pragma unroll
    for (int ks = 0; ks < 4; ++ks) aX[ks] = ld8(Arow + ks * 32 + quad * 8);

    // staging geometry: wave w owns LDS bytes [w*8K,(w+1)*8K) of each 32 KB buf.
    // Linear LDS dest (DMA: uniform base + lane*16); swizzle folded into the
    // per-lane global source offset (same involution as the read side).
    int isA = (w < 2);
    uint32_t gsoff[8];
#pragma unroll
    for (int i = 0; i < 8; ++i) {
        uint32_t o = (uint32_t)(w * 8 + i) * 1024 + (uint32_t)lane * 16;
        if (isA) {                                    // B rows of 256 B, contiguous tile
            gsoff[i] = o ^ (((o >> 8) & 7) << 4);
        } else {                                      // BT rows of 128 B, global stride 2048 B
            uint32_t j = o - 16384;
            gsoff[i] = (j >> 7) * 2048 + ((j & 127) ^ (((j >> 7) & 7) << 4));
        }
    }
    const char* srcbase = (const char*)(isA ? Bmat : BTmat);
    uint32_t tstride = isA ? 16384u : 128u;

#define STAGE_ISSUE(buf, tt_)                                                        \
    do {                                                                             \
        const char* gsb_ = srcbase + (size_t)(tt_) * tstride;                        \
        _Pragma("unroll")                                                            \
        for (int i_ = 0; i_ < 8; ++i_) {                                             \
            __builtin_amdgcn_global_load_lds(                                        \
                (gvoid_t*)(gsb_ + gsoff[i_]),                                        \
                (lvoid_t*)((__attribute__((address_space(3))) char*)                 \
                               ((char*)&stage[buf][0]) + (uint32_t)(w * 8 + i_) * 1024), \
                16, 0, 0);                                                           \
        }                                                                            \
    } while (0)

    // prologue: stage tile 0
    STAGE_ISSUE(0, 0);
    asm volatile("s_waitcnt vmcnt(0)" ::: "memory");
    __builtin_amdgcn_sched_barrier(0);
    __builtin_amdgcn_s_barrier();
    __builtin_amdgcn_sched_barrier(0);

    f32x4 accU[8];
#pragma unroll
    for (int df = 0; df < 8; ++df) accU[df] = {0.f, 0.f, 0.f, 0.f};
    float rowsum[4] = {0.f, 0.f, 0.f, 0.f};
    uint32_t xq = (uint32_t)(l16 & 7) << 4;           // read-side swizzle term
    int cur = 0;

#pragma unroll 1
    for (int tt = 0; tt < 16; ++tt) {
        // 1. DMA next tile into the free buffer; latency spans the compute phase
        if (tt < 15) STAGE_ISSUE(cur ^ 1, tt + 1);
        __builtin_amdgcn_sched_barrier(0);

        const char* sb = (const char*)&stage[cur][0];
        // 2. GEMM1: S = A @ Btile^T
        f32x4 accS[4];
#pragma unroll
        for (int mf = 0; mf < 4; ++mf) accS[mf] = {0.f, 0.f, 0.f, 0.f};
#pragma unroll
        for (int ks = 0; ks < 4; ++ks) {
            bf16x8 bY[4];
#pragma unroll
            for (int mf = 0; mf < 4; ++mf)
                bY[mf] = *reinterpret_cast<const bf16x8*>(
                    sb + (uint32_t)(mf * 16 + l16) * 256 + (((uint32_t)(ks * 64 + quad * 16)) ^ xq));
#pragma unroll
            for (int mf = 0; mf < 4; ++mf)
                accS[mf] = __builtin_amdgcn_mfma_f32_16x16x32_bf16(aX[ks], bY[mf], accS[mf], 0, 0, 0);
        }
        // 3. epilogue: E always; s = ESHIFT + ln(E) - 0.5 (role 0)
#pragma unroll
        for (int mf = 0; mf < 4; ++mf) {
#pragma unroll
            for (int r = 0; r < 4; ++r) {
                float x = accS[mf][r];
                float E = __builtin_amdgcn_exp2f((x - ESHIFT) * LOG2E) + ESHIFT_C;
                bf16 Eb = (bf16)E;
                rowsum[r] += (float)Eb;
                Et[w][quad * 4 + r][mf * 16 + l16] = Eb;
                if (role == 0) {
                    float sp = fmaf(LN2, __builtin_amdgcn_logf(E), ESHIFT - 0.5f);
                    s_b[(size_t)(rbase + quad * 4 + r) * MM + tt * 64 + mf * 16 + l16] = sp;
                }
            }
        }
        // 4. GEMM2: U += E @ Btile
#pragma unroll
        for (int half = 0; half < 2; ++half) {
            bf16x8 aE = *reinterpret_cast<const bf16x8*>(&Et[w][l16][half * 32 + quad * 8]);
            bf16x8 bT[8];
#pragma unroll
            for (int df = 0; df < 8; ++df)
                bT[df] = *reinterpret_cast<const bf16x8*>(
                    sb + 16384 + (uint32_t)(df * 16 + l16) * 128 + (((uint32_t)(half * 64 + quad * 16)) ^ xq));
#pragma unroll
            for (int df = 0; df < 8; ++df)
                accU[df] = __builtin_amdgcn_mfma_f32_16x16x32_bf16(aE, bT[df], accU[df], 0, 0, 0);
        }
        // 5. next tile's DMA must have landed before any wave reads it
        __builtin_amdgcn_sched_barrier(0);
        asm volatile("s_waitcnt vmcnt(0)" ::: "memory");
        __builtin_amdgcn_sched_barrier(0);
        __builtin_amdgcn_s_barrier();
        __builtin_amdgcn_sched_barrier(0);
        cur ^= 1;
    }
#undef STAGE_ISSUE

    float inv[4];
#pragma unroll
    for (int r = 0; r < 4; ++r) {
        float rs = rowsum[r];
        rs += __shfl_xor(rs, 1); rs += __shfl_xor(rs, 2);
        rs += __shfl_xor(rs, 4); rs += __shfl_xor(rs, 8);
        inv[r] = 1.f / rs;
    }
#pragma unroll
    for (int df = 0; df < 8; ++df)
#pragma unroll
        for (int r = 0; r < 4; ++r)
            outp[((size_t)b * 1024 + rbase + quad * 4 + r) * DD + df * 16 + l16] = accU[df][r] * inv[r];
}

extern "C" void kernel_launch(void* const* d_in, const int* in_sizes, int n_in,
                              void* d_out, int out_size, void* d_ws, size_t ws_size,
                              hipStream_t stream) {
    const float* Xs = (const float*)d_in[0];
    const float* Ys = (const float*)d_in[1];
    const float* W  = (const float*)d_in[2];
    const float* Aw = (const float*)d_in[3];
    const float* Ab = (const float*)d_in[4];

    char* ws = (char*)d_ws;
    bf16*  Xc     = (bf16*)(ws);                 //  8 MB
    bf16*  Ysb    = (bf16*)(ws + 8388608);       //  8 MB
    bf16*  YsT    = (bf16*)(ws + 16777216);      //  8 MB
    bf16*  XsT    = (bf16*)(ws + 25165824);      //  8 MB

    float* out_x = (float*)d_out;
    float* out_y = out_x + (size_t)BB * NN * DD;
    float* out_s = out_y + (size_t)BB * MM * DD;

    k_prep<<<dim3(2048), 256, 0, stream>>>(Xs, Ys, Ysb, YsT, XsT);
    k_coeff<<<dim3(512), 256, 0, stream>>>(Xs, W, Aw, Ab, Xc);
    k_main<<<dim3(32, BB), 256, 0, stream>>>(Xc, Ysb, YsT, XsT, out_x, out_y, out_s);
}